// Round 8
// baseline (1379.373 us; speedup 1.0000x reference)
//
#include <hip/hip_runtime.h>
#include <hip/hip_fp16.h>

// N=100000 nodes, 64 in-feats, 32 hidden, E=3200000 edges per type.
// Single fused persistent kernel: count -> (dinv+xw+seed) -> pk_f16 scatter
// -> epilogue, with device-scope grid barriers. Targets the ~300us of
// inter-kernel overhead that R5-R7 could not remove (scatter itself is pinned
// at the 310 G atomic-op/s ceiling: 102.4M pk ops = ~330us, measured 3x).
// XCD-L2 non-coherence handled by agent-scope atomics for ALL cross-phase
// data; barriers are one-shot counters zeroed by hipMemsetAsync per launch.

#define SCOPE_AGENT __HIP_MEMORY_SCOPE_AGENT

__device__ __forceinline__ int ld_agent_i32(const int* p) {
    return __hip_atomic_load(const_cast<int*>(p), __ATOMIC_RELAXED, SCOPE_AGENT);
}
__device__ __forceinline__ unsigned ld_agent_u32(const unsigned* p) {
    return __hip_atomic_load(const_cast<unsigned*>(p), __ATOMIC_RELAXED, SCOPE_AGENT);
}
__device__ __forceinline__ void st_agent_u32(unsigned* p, unsigned v) {
    __hip_atomic_store(p, v, __ATOMIC_RELAXED, SCOPE_AGENT);
}

// One-shot grid barrier: counter pre-zeroed by host memset before launch.
__device__ __forceinline__ void grid_barrier(int* ctr, int nblk) {
    __syncthreads();
    if (threadIdx.x == 0) {
        __threadfence();
        __hip_atomic_fetch_add(ctr, 1, __ATOMIC_ACQ_REL, SCOPE_AGENT);
        while (__hip_atomic_load(ctr, __ATOMIC_ACQUIRE, SCOPE_AGENT) < nblk) {
            __builtin_amdgcn_s_sleep(1);
        }
        __threadfence();
    }
    __syncthreads();
}

__global__ __launch_bounds__(256, 4)
void fused_kernel(const float* __restrict__ x,
                  const int* __restrict__ ei_n, const int* __restrict__ ei_s,
                  const float* __restrict__ Wn, const float* __restrict__ Ws,
                  const float* __restrict__ b_n, const float* __restrict__ b_s,
                  const float* __restrict__ W_lin, const float* __restrict__ b_lin,
                  int* __restrict__ barriers, int* __restrict__ cnt,
                  unsigned* __restrict__ xws, unsigned* __restrict__ acc,
                  float* __restrict__ out, int N, int En, int Es) {
    __shared__ float wn[64 * 32];
    __shared__ float wsm[64 * 32];
    for (int i = threadIdx.x; i < 64 * 32; i += 256) {   // used after barrier 0
        wn[i] = Wn[i];
        wsm[i] = Ws[i];
    }

    const int tid = blockIdx.x * 256 + threadIdx.x;
    const int nthreads = gridDim.x * 256;
    const int Etot = En + Es;
    const int nblk = gridDim.x;

    // ---- Phase 1: degree count (device-scope int atomics) ----
    for (int i = tid; i < Etot; i += nthreads) {
        int idx;
        if (i < En) idx = ei_n[En + i];
        else        idx = N + ei_s[Es + (i - En)];
        atomicAdd(&cnt[idx], 1);
    }
    grid_barrier(&barriers[0], nblk);

    // ---- Phase 2: xws = (x@W)*rsqrt(deg+1) packed f16x2; acc seeded (self-loop) ----
    {
        int lane = threadIdx.x & 31;
        int wid = threadIdx.x >> 5;                 // 8 node-groups per block
        int ngroups = nblk * 8;
        for (int node = blockIdx.x * 8 + wid; node < N; node += ngroups) {
            const float4* x4 = (const float4*)(x + (size_t)node * 64);
            float an = 0.f, as = 0.f;
#pragma unroll
            for (int k4 = 0; k4 < 16; ++k4) {
                float4 xv = x4[k4];
                int k = k4 * 4;
                an += xv.x * wn[(k + 0) * 32 + lane] + xv.y * wn[(k + 1) * 32 + lane]
                    + xv.z * wn[(k + 2) * 32 + lane] + xv.w * wn[(k + 3) * 32 + lane];
                as += xv.x * wsm[(k + 0) * 32 + lane] + xv.y * wsm[(k + 1) * 32 + lane]
                    + xv.z * wsm[(k + 2) * 32 + lane] + xv.w * wsm[(k + 3) * 32 + lane];
            }
            float vn = an * rsqrtf((float)ld_agent_i32(&cnt[node]) + 1.0f);
            float vs = as * rsqrtf((float)ld_agent_i32(&cnt[N + node]) + 1.0f);
            int sl = lane & 15;
            float vn0 = __shfl(vn, 2 * sl, 32);
            float vn1 = __shfl(vn, 2 * sl + 1, 32);
            float vs0 = __shfl(vs, 2 * sl, 32);
            float vs1 = __shfl(vs, 2 * sl + 1, 32);
            if (lane < 16) {
                __half2 hn = __floats2half2_rn(vn0, vn1);
                __half2 hs = __floats2half2_rn(vs0, vs1);
                unsigned un = *(unsigned*)&hn;
                unsigned us = *(unsigned*)&hs;
                size_t on = (size_t)node * 16 + sl;
                size_t os = ((size_t)N + node) * 16 + sl;
                st_agent_u32(&xws[on], un);
                st_agent_u32(&acc[on], un);
                st_agent_u32(&xws[os], us);
                st_agent_u32(&acc[os], us);
            }
        }
    }
    grid_barrier(&barriers[1], nblk);

    // ---- Phase 3: push-scatter, 16 lanes/edge, global_atomic_pk_add_f16 ----
    {
        int sl = threadIdx.x & 15;
        int g = tid >> 4;
        int ngr = nthreads >> 4;
        for (int e = g; e < Etot; e += ngr) {
            int src, dst;
            size_t base;
            if (e < En) {
                src = ei_n[e]; dst = ei_n[En + e]; base = 0;
            } else {
                int e2 = e - En;
                src = ei_s[e2]; dst = ei_s[Es + e2]; base = (size_t)N;
            }
            unsigned w = ld_agent_u32(&xws[(base + src) * 16 + sl]);
            __half2 hw = *(__half2*)&w;
            unsafeAtomicAdd((__half2*)&acc[(base + dst) * 16 + sl], hw);
        }
    }
    grid_barrier(&barriers[2], nblk);

    // ---- Phase 4: epilogue ----
    {
        int sl = threadIdx.x & 15;
        float bn0 = b_n[2 * sl], bn1 = b_n[2 * sl + 1];
        float bs0 = b_s[2 * sl], bs1 = b_s[2 * sl + 1];
        float wl0 = W_lin[2 * sl], wl1 = W_lin[2 * sl + 1];
        float bl = b_lin[0];
        int g = tid >> 4;
        int gs = nthreads >> 4;
        for (int node = g; node < N; node += gs) {
            unsigned uan = ld_agent_u32(&acc[(size_t)node * 16 + sl]);
            unsigned uas = ld_agent_u32(&acc[((size_t)N + node) * 16 + sl]);
            __half2 han = *(__half2*)&uan;
            __half2 has = *(__half2*)&uas;
            float2 an = __half22float2(han);
            float2 av = __half22float2(has);
            float dn = rsqrtf((float)ld_agent_i32(&cnt[node]) + 1.0f);
            float dsv = rsqrtf((float)ld_agent_i32(&cnt[N + node]) + 1.0f);
            float h0 = an.x * dn + bn0 + av.x * dsv + bs0;
            float h1 = an.y * dn + bn1 + av.y * dsv + bs1;
            float p = fmaxf(h0, 0.f) * wl0 + fmaxf(h1, 0.f) * wl1;
#pragma unroll
            for (int off = 8; off > 0; off >>= 1) p += __shfl_xor(p, off, 16);
            if (sl == 0) out[node] = p + bl;
        }
    }
}

extern "C" void kernel_launch(void* const* d_in, const int* in_sizes, int n_in,
                              void* d_out, int out_size, void* d_ws, size_t ws_size,
                              hipStream_t stream) {
    const float* x     = (const float*)d_in[0];
    const int*   ei_n  = (const int*)d_in[1];
    const int*   ei_s  = (const int*)d_in[2];
    const float* W_n   = (const float*)d_in[3];
    const float* b_n   = (const float*)d_in[4];
    const float* W_s   = (const float*)d_in[5];
    const float* b_s   = (const float*)d_in[6];
    const float* W_lin = (const float*)d_in[7];
    const float* b_lin = (const float*)d_in[8];
    float* out = (float*)d_out;

    const int N  = in_sizes[0] / 64;   // 100000
    const int En = in_sizes[1] / 2;    // 3200000
    const int Es = in_sizes[2] / 2;    // 3200000
    const int M  = 2 * N;

    // Workspace (4B words), ~25.6 MB:
    // barriers[4] | cnt[2N] | xws[2N*16] | acc[2N*16]
    int*      barriers = (int*)d_ws;
    int*      cnt      = barriers + 4;
    unsigned* xws      = (unsigned*)(cnt + (size_t)M);
    unsigned* acc      = xws + (size_t)16 * M;

    // Co-residency-safe grid: blocks/CU from the occupancy API (host-only,
    // capture-safe), 256 CUs on gfx950. Phases grid-stride, so any size works.
    int occ = 0;
    if (hipOccupancyMaxActiveBlocksPerMultiprocessor(&occ, fused_kernel, 256, 0)
            != hipSuccess || occ < 1)
        occ = 1;
    if (occ > 8) occ = 8;
    int nblk = 256 * occ;

    // Zero barriers + cnt in one contiguous memset (acc seeded in-kernel).
    hipMemsetAsync(barriers, 0, (4 + (size_t)M) * sizeof(int), stream);

    fused_kernel<<<nblk, 256, 0, stream>>>(x, ei_n, ei_s, W_n, W_s, b_n, b_s,
                                           W_lin, b_lin, barriers, cnt, xws, acc,
                                           out, N, En, Es);
}

// Round 9
// 730.054 us; speedup vs baseline: 1.8894x; 1.8894x over previous
//
#include <hip/hip_runtime.h>
#include <hip/hip_fp16.h>

// N=100000 nodes, 64 in-feats, 32 hidden, E=3200000 edges per type.
// R5 structure (best: 727us) with the pk_f16 push-scatter split into FOUR
// quarter-dispatches (~82us each). Purpose: scatter instances occupied all
// five rocprof top-5 slots (330us each), hiding where the ~397us non-scatter
// remainder lives. With quarters at ~82us, any hidden kernel >=85us must
// surface. Same total atomic ops (102.4M), branchless per-dispatch.
// R8 lesson: full fusion + agent-scope traffic = 831MB writes, 49% occupancy,
// 2x regression. R6/R7 lessons: scatter ceiling (310 G pk-ops/s) is invariant
// to WG count and count-striping.

__global__ void count_kernel(const int* __restrict__ ei_n, const int* __restrict__ ei_s,
                             int* __restrict__ cnt, int N, int En, int Es) {
    int gid = blockIdx.x * blockDim.x + threadIdx.x;
    if (gid < En) {
        atomicAdd(&cnt[ei_n[En + gid]], 1);
    } else if (gid < En + Es) {
        int e = gid - En;
        atomicAdd(&cnt[N + ei_s[Es + e]], 1);
    }
}

// xws[type][node] = (x[node] @ W_type) * rsqrt(deg+1), packed __half2
// (feats 2sl, 2sl+1 in word sl). acc seeded with same value (self-loop msg).
__global__ void xw_kernel(const float* __restrict__ x,
                          const float* __restrict__ Wn, const float* __restrict__ Ws,
                          const int* __restrict__ cnt,
                          __half2* __restrict__ xws, __half2* __restrict__ acc, int N) {
    __shared__ float wn[64 * 32];
    __shared__ float wsm[64 * 32];
    for (int i = threadIdx.x; i < 64 * 32; i += blockDim.x) {
        wn[i] = Wn[i];
        wsm[i] = Ws[i];
    }
    __syncthreads();
    int lane = threadIdx.x & 31;
    int node = blockIdx.x * (blockDim.x >> 5) + (threadIdx.x >> 5);
    if (node >= N) return;

    const float4* x4 = (const float4*)(x + (size_t)node * 64);
    float an = 0.f, as = 0.f;
#pragma unroll
    for (int k4 = 0; k4 < 16; ++k4) {
        float4 xv = x4[k4];
        int k = k4 * 4;
        an += xv.x * wn[(k + 0) * 32 + lane] + xv.y * wn[(k + 1) * 32 + lane]
            + xv.z * wn[(k + 2) * 32 + lane] + xv.w * wn[(k + 3) * 32 + lane];
        as += xv.x * wsm[(k + 0) * 32 + lane] + xv.y * wsm[(k + 1) * 32 + lane]
            + xv.z * wsm[(k + 2) * 32 + lane] + xv.w * wsm[(k + 3) * 32 + lane];
    }
    float vn = an * rsqrtf((float)cnt[node] + 1.0f);
    float vs = as * rsqrtf((float)cnt[N + node] + 1.0f);
    int sl = lane & 15;
    float vn0 = __shfl(vn, 2 * sl, 32);
    float vn1 = __shfl(vn, 2 * sl + 1, 32);
    float vs0 = __shfl(vs, 2 * sl, 32);
    float vs1 = __shfl(vs, 2 * sl + 1, 32);
    if (lane < 16) {
        __half2 hn = __floats2half2_rn(vn0, vn1);
        __half2 hs = __floats2half2_rn(vs0, vs1);
        size_t on = (size_t)node * 16 + sl;
        size_t os = ((size_t)N + node) * 16 + sl;
        xws[on] = hn;
        acc[on] = hn;
        xws[os] = hs;
        acc[os] = hs;
    }
}

// Scatter a contiguous edge range [e0,e1) of ONE edge type (branchless).
// 16 lanes per edge: gather 64B packed msg row, pk_add_f16 into acc[dst].
__global__ void scatter_kernel(const int* __restrict__ ei_src, const int* __restrict__ ei_dst,
                               const __half2* __restrict__ xws, __half2* __restrict__ acc,
                               int e0, int e1) {
    unsigned int gid = blockIdx.x * blockDim.x + threadIdx.x;
    int e = e0 + (int)(gid >> 4);
    int sl = gid & 15;
    if (e >= e1) return;
    int src = ei_src[e];
    int dst = ei_dst[e];
    __half2 w = xws[(size_t)src * 16 + sl];
    unsafeAtomicAdd(&acc[(size_t)dst * 16 + sl], w);   // global_atomic_pk_add_f16
}

// out[d] = dot(relu(acc_n*dinv_n + b_n + acc_s*dinv_s + b_s), W_lin) + b_lin
__global__ void epilogue_kernel(const __half2* __restrict__ acc, const int* __restrict__ cnt,
                                const float* __restrict__ b_n, const float* __restrict__ b_s,
                                const float* __restrict__ W_lin, const float* __restrict__ b_lin,
                                float* __restrict__ out, int N) {
    int gid = blockIdx.x * blockDim.x + threadIdx.x;
    int node = gid >> 4, sl = gid & 15;
    if (node >= N) return;
    float2 an = __half22float2(acc[(size_t)node * 16 + sl]);
    float2 as = __half22float2(acc[((size_t)N + node) * 16 + sl]);
    float dn = rsqrtf((float)cnt[node] + 1.0f);
    float dsv = rsqrtf((float)cnt[N + node] + 1.0f);
    float h0 = an.x * dn + b_n[2 * sl] + as.x * dsv + b_s[2 * sl];
    float h1 = an.y * dn + b_n[2 * sl + 1] + as.y * dsv + b_s[2 * sl + 1];
    float p = fmaxf(h0, 0.f) * W_lin[2 * sl] + fmaxf(h1, 0.f) * W_lin[2 * sl + 1];
#pragma unroll
    for (int off = 8; off > 0; off >>= 1) p += __shfl_xor(p, off, 16);
    if (sl == 0) out[node] = p + b_lin[0];
}

extern "C" void kernel_launch(void* const* d_in, const int* in_sizes, int n_in,
                              void* d_out, int out_size, void* d_ws, size_t ws_size,
                              hipStream_t stream) {
    const float* x     = (const float*)d_in[0];
    const int*   ei_n  = (const int*)d_in[1];
    const int*   ei_s  = (const int*)d_in[2];
    const float* W_n   = (const float*)d_in[3];
    const float* b_n   = (const float*)d_in[4];
    const float* W_s   = (const float*)d_in[5];
    const float* b_s   = (const float*)d_in[6];
    const float* W_lin = (const float*)d_in[7];
    const float* b_lin = (const float*)d_in[8];
    float* out = (float*)d_out;

    const int N    = in_sizes[0] / 64;   // 100000
    const int En   = in_sizes[1] / 2;    // 3200000
    const int Es   = in_sizes[2] / 2;    // 3200000
    const int Etot = En + Es;
    const int M    = 2 * N;

    // Workspace (4B words), ~26.4 MB: cnt[2N] | xws[2N*16 half2] | acc[2N*16 half2]
    int*     cnt = (int*)d_ws;
    __half2* xws = (__half2*)(cnt + (size_t)M);
    __half2* acc = xws + (size_t)16 * M;

    hipMemsetAsync(cnt, 0, (size_t)M * sizeof(int), stream);

    count_kernel<<<(Etot + 255) / 256, 256, 0, stream>>>(ei_n, ei_s, cnt, N, En, Es);

    xw_kernel<<<(N + 7) / 8, 256, 0, stream>>>(x, W_n, W_s, cnt, xws, acc, N);

    // Scatter in four quarter-dispatches (diagnostic: frees rocprof top-5
    // slots so any hidden >=85us kernel must surface). Same 102.4M pk ops.
    {
        int h_n = En / 2, h_s = Es / 2;
        auto blocks = [](int ne) { return (int)(((size_t)ne * 16 + 255) / 256); };
        scatter_kernel<<<blocks(h_n), 256, 0, stream>>>(ei_n, ei_n + En, xws, acc, 0, h_n);
        scatter_kernel<<<blocks(En - h_n), 256, 0, stream>>>(ei_n, ei_n + En, xws, acc, h_n, En);
        scatter_kernel<<<blocks(h_s), 256, 0, stream>>>(ei_s, ei_s + Es, xws + (size_t)16 * N,
                                                        acc + (size_t)16 * N, 0, h_s);
        scatter_kernel<<<blocks(Es - h_s), 256, 0, stream>>>(ei_s, ei_s + Es, xws + (size_t)16 * N,
                                                             acc + (size_t)16 * N, h_s, Es);
    }

    epilogue_kernel<<<(int)(((size_t)N * 16 + 255) / 256), 256, 0, stream>>>(
        acc, cnt, b_n, b_s, W_lin, b_lin, out, N);
}

// Round 10
// 529.596 us; speedup vs baseline: 2.6046x; 1.3785x over previous
//
#include <hip/hip_runtime.h>
#include <hip/hip_fp16.h>

// N=100000 nodes, 64 in-feats, 32 hidden, E=3200000 edges per type.
// Model (R9-calibrated): memory-side atomics cost ~12 cyc/channel per 64B
// LINE-transaction, independent of ops or bytes within the line.
//   scatter: 6.4M line-transactions (16-lane pk_f16 rows) = ~330us  [floor]
//   count:   6.4M line-transactions (single 4B atomics)   = ~251us  [this round's target]
// Fix: LDS-privatized range histogram -> line-dense flush (~0.5M lines).
// Rest identical to R9 (best 727-730us family).

#define HRANGE 32768   // nodes per histogram range (128 KB LDS of int)

__global__ __launch_bounds__(1024, 1)
void hist_kernel(const int* __restrict__ dst_n, const int* __restrict__ dst_s,
                 int* __restrict__ cnt, int N, int E) {
    __shared__ int h[HRANGE];
    for (int i = threadIdx.x; i < HRANGE; i += 1024) h[i] = 0;
    __syncthreads();

    const int range_lo = blockIdx.x * HRANGE;
    const int type = blockIdx.z;
    const int* __restrict__ dst = type ? dst_s : dst_n;
    int* __restrict__ cplane = cnt + (size_t)type * N;

    const int S = gridDim.y;
    const int per = (E + S - 1) / S;
    const int e0 = blockIdx.y * per;
    const int e1 = min(e0 + per, E);
    for (int i = e0 + (int)threadIdx.x; i < e1; i += 1024) {
        int d = dst[i] - range_lo;
        if ((unsigned)d < (unsigned)HRANGE) atomicAdd(&h[d], 1);
    }
    __syncthreads();

    const int hi = min(range_lo + HRANGE, N) - range_lo;
    for (int i = threadIdx.x; i < hi; i += 1024) {
        int v = h[i];
        if (v) atomicAdd(&cplane[range_lo + i], v);   // line-dense flush
    }
}

// xws[type][node] = (x[node] @ W_type) * rsqrt(deg+1), packed __half2
// (feats 2sl, 2sl+1 in word sl). acc seeded with same value (self-loop msg).
__global__ void xw_kernel(const float* __restrict__ x,
                          const float* __restrict__ Wn, const float* __restrict__ Ws,
                          const int* __restrict__ cnt,
                          __half2* __restrict__ xws, __half2* __restrict__ acc, int N) {
    __shared__ float wn[64 * 32];
    __shared__ float wsm[64 * 32];
    for (int i = threadIdx.x; i < 64 * 32; i += blockDim.x) {
        wn[i] = Wn[i];
        wsm[i] = Ws[i];
    }
    __syncthreads();
    int lane = threadIdx.x & 31;
    int node = blockIdx.x * (blockDim.x >> 5) + (threadIdx.x >> 5);
    if (node >= N) return;

    const float4* x4 = (const float4*)(x + (size_t)node * 64);
    float an = 0.f, as = 0.f;
#pragma unroll
    for (int k4 = 0; k4 < 16; ++k4) {
        float4 xv = x4[k4];
        int k = k4 * 4;
        an += xv.x * wn[(k + 0) * 32 + lane] + xv.y * wn[(k + 1) * 32 + lane]
            + xv.z * wn[(k + 2) * 32 + lane] + xv.w * wn[(k + 3) * 32 + lane];
        as += xv.x * wsm[(k + 0) * 32 + lane] + xv.y * wsm[(k + 1) * 32 + lane]
            + xv.z * wsm[(k + 2) * 32 + lane] + xv.w * wsm[(k + 3) * 32 + lane];
    }
    float vn = an * rsqrtf((float)cnt[node] + 1.0f);
    float vs = as * rsqrtf((float)cnt[N + node] + 1.0f);
    int sl = lane & 15;
    float vn0 = __shfl(vn, 2 * sl, 32);
    float vn1 = __shfl(vn, 2 * sl + 1, 32);
    float vs0 = __shfl(vs, 2 * sl, 32);
    float vs1 = __shfl(vs, 2 * sl + 1, 32);
    if (lane < 16) {
        __half2 hn = __floats2half2_rn(vn0, vn1);
        __half2 hs = __floats2half2_rn(vs0, vs1);
        size_t on = (size_t)node * 16 + sl;
        size_t os = ((size_t)N + node) * 16 + sl;
        xws[on] = hn;
        acc[on] = hn;
        xws[os] = hs;
        acc[os] = hs;
    }
}

// Push-scatter one edge type (branchless): 16 lanes/edge, 64B gather,
// global_atomic_pk_add_f16 into acc[dst].
__global__ void scatter_kernel(const int* __restrict__ ei_src, const int* __restrict__ ei_dst,
                               const __half2* __restrict__ xws, __half2* __restrict__ acc,
                               int E) {
    unsigned int gid = blockIdx.x * blockDim.x + threadIdx.x;
    int e = (int)(gid >> 4);
    int sl = gid & 15;
    if (e >= E) return;
    int src = ei_src[e];
    int dst = ei_dst[e];
    __half2 w = xws[(size_t)src * 16 + sl];
    unsafeAtomicAdd(&acc[(size_t)dst * 16 + sl], w);   // global_atomic_pk_add_f16
}

// out[d] = dot(relu(acc_n*dinv_n + b_n + acc_s*dinv_s + b_s), W_lin) + b_lin
__global__ void epilogue_kernel(const __half2* __restrict__ acc, const int* __restrict__ cnt,
                                const float* __restrict__ b_n, const float* __restrict__ b_s,
                                const float* __restrict__ W_lin, const float* __restrict__ b_lin,
                                float* __restrict__ out, int N) {
    int gid = blockIdx.x * blockDim.x + threadIdx.x;
    int node = gid >> 4, sl = gid & 15;
    if (node >= N) return;
    float2 an = __half22float2(acc[(size_t)node * 16 + sl]);
    float2 as = __half22float2(acc[((size_t)N + node) * 16 + sl]);
    float dn = rsqrtf((float)cnt[node] + 1.0f);
    float dsv = rsqrtf((float)cnt[N + node] + 1.0f);
    float h0 = an.x * dn + b_n[2 * sl] + as.x * dsv + b_s[2 * sl];
    float h1 = an.y * dn + b_n[2 * sl + 1] + as.y * dsv + b_s[2 * sl + 1];
    float p = fmaxf(h0, 0.f) * W_lin[2 * sl] + fmaxf(h1, 0.f) * W_lin[2 * sl + 1];
#pragma unroll
    for (int off = 8; off > 0; off >>= 1) p += __shfl_xor(p, off, 16);
    if (sl == 0) out[node] = p + b_lin[0];
}

extern "C" void kernel_launch(void* const* d_in, const int* in_sizes, int n_in,
                              void* d_out, int out_size, void* d_ws, size_t ws_size,
                              hipStream_t stream) {
    const float* x     = (const float*)d_in[0];
    const int*   ei_n  = (const int*)d_in[1];
    const int*   ei_s  = (const int*)d_in[2];
    const float* W_n   = (const float*)d_in[3];
    const float* b_n   = (const float*)d_in[4];
    const float* W_s   = (const float*)d_in[5];
    const float* b_s   = (const float*)d_in[6];
    const float* W_lin = (const float*)d_in[7];
    const float* b_lin = (const float*)d_in[8];
    float* out = (float*)d_out;

    const int N  = in_sizes[0] / 64;   // 100000
    const int En = in_sizes[1] / 2;    // 3200000
    const int Es = in_sizes[2] / 2;    // 3200000
    const int M  = 2 * N;

    // Workspace (4B words), ~26.4 MB: cnt[2N] | xws[2N*16 half2] | acc[2N*16 half2]
    int*     cnt = (int*)d_ws;
    __half2* xws = (__half2*)(cnt + (size_t)M);
    __half2* acc = xws + (size_t)16 * M;

    hipMemsetAsync(cnt, 0, (size_t)M * sizeof(int), stream);

    {
        int nr = (N + HRANGE - 1) / HRANGE;   // 4
        dim3 grid(nr, 32, 2);                 // 256 blocks, 1/CU (128 KB LDS)
        hist_kernel<<<grid, 1024, 0, stream>>>(ei_n + En, ei_s + Es, cnt, N, En);
    }

    xw_kernel<<<(N + 7) / 8, 256, 0, stream>>>(x, W_n, W_s, cnt, xws, acc, N);

    {
        auto blocks = [](int ne) { return (int)(((size_t)ne * 16 + 255) / 256); };
        scatter_kernel<<<blocks(En), 256, 0, stream>>>(ei_n, ei_n + En, xws, acc, En);
        scatter_kernel<<<blocks(Es), 256, 0, stream>>>(ei_s, ei_s + Es,
                                                       xws + (size_t)16 * N,
                                                       acc + (size_t)16 * N, Es);
    }

    epilogue_kernel<<<(int)(((size_t)N * 16 + 255) / 256), 256, 0, stream>>>(
        acc, cnt, b_n, b_s, W_lin, b_lin, out, N);
}

// Round 11
// 498.125 us; speedup vs baseline: 2.7691x; 1.0632x over previous
//
#include <hip/hip_runtime.h>
#include <hip/hip_fp16.h>

// N=100000 nodes, 64 in-feats, 32 hidden, E=3200000 edges per type.
// Calibrated model (R9/R10): memory-side atomic RMW costs ~1 line-transaction
// per 64B line touched (~25 G lines/s device-wide); ops within a line are
// nearly free. Push-scatter floor = 6.4M edge-lines ~= 250-330us. Pipeline:
//   memset(5) -> hist (LDS-privatized, line-dense flush, ~45us)
//   -> xw (GEMM + f16x2 pack, pre-scaled by dinv[src], seeds acc, ~35us)
//   -> merged scatter (pk_f16, 2-edge ILP, ~330us) -> epilogue (~25us).

#define HRANGE 32768   // nodes per histogram range (128 KB LDS of int)

__global__ __launch_bounds__(1024, 1)
void hist_kernel(const int* __restrict__ dst_n, const int* __restrict__ dst_s,
                 int* __restrict__ cnt, int N, int E) {
    __shared__ int h[HRANGE];
    for (int i = threadIdx.x; i < HRANGE; i += 1024) h[i] = 0;
    __syncthreads();

    const int range_lo = blockIdx.x * HRANGE;
    const int type = blockIdx.z;
    const int* __restrict__ dst = type ? dst_s : dst_n;
    int* __restrict__ cplane = cnt + (size_t)type * N;

    const int S = gridDim.y;
    int per = (E + S - 1) / S;
    per = (per + 3) & ~3;                       // keep 16B alignment per slice
    const int e0 = blockIdx.y * per;
    const int e1 = min(e0 + per, E);

    // int4 stream: 4 dsts per thread-iteration
    int i = e0 + (int)threadIdx.x * 4;
    for (; i + 3 < e1; i += 1024 * 4) {
        int4 v = *(const int4*)(dst + i);
        int d0 = v.x - range_lo, d1 = v.y - range_lo,
            d2 = v.z - range_lo, d3 = v.w - range_lo;
        if ((unsigned)d0 < (unsigned)HRANGE) atomicAdd(&h[d0], 1);
        if ((unsigned)d1 < (unsigned)HRANGE) atomicAdd(&h[d1], 1);
        if ((unsigned)d2 < (unsigned)HRANGE) atomicAdd(&h[d2], 1);
        if ((unsigned)d3 < (unsigned)HRANGE) atomicAdd(&h[d3], 1);
    }
    for (; i < e1; ++i) {                       // scalar tail
        int d = dst[i] - range_lo;
        if ((unsigned)d < (unsigned)HRANGE) atomicAdd(&h[d], 1);
    }
    __syncthreads();

    const int hi = min(range_lo + HRANGE, N) - range_lo;
    for (int j = threadIdx.x; j < hi; j += 1024) {
        int v = h[j];
        if (v) atomicAdd(&cplane[range_lo + j], v);   // line-dense flush
    }
}

// xws[type][node] = (x[node] @ W_type) * rsqrt(deg+1), packed __half2
// (feats 2sl, 2sl+1 in word sl). acc seeded with same value (self-loop msg).
__global__ void xw_kernel(const float* __restrict__ x,
                          const float* __restrict__ Wn, const float* __restrict__ Ws,
                          const int* __restrict__ cnt,
                          __half2* __restrict__ xws, __half2* __restrict__ acc, int N) {
    __shared__ float wn[64 * 32];
    __shared__ float wsm[64 * 32];
    for (int i = threadIdx.x; i < 64 * 32; i += blockDim.x) {
        wn[i] = Wn[i];
        wsm[i] = Ws[i];
    }
    __syncthreads();
    int lane = threadIdx.x & 31;
    int node = blockIdx.x * (blockDim.x >> 5) + (threadIdx.x >> 5);
    if (node >= N) return;

    const float4* x4 = (const float4*)(x + (size_t)node * 64);
    float an = 0.f, as = 0.f;
#pragma unroll
    for (int k4 = 0; k4 < 16; ++k4) {
        float4 xv = x4[k4];
        int k = k4 * 4;
        an += xv.x * wn[(k + 0) * 32 + lane] + xv.y * wn[(k + 1) * 32 + lane]
            + xv.z * wn[(k + 2) * 32 + lane] + xv.w * wn[(k + 3) * 32 + lane];
        as += xv.x * wsm[(k + 0) * 32 + lane] + xv.y * wsm[(k + 1) * 32 + lane]
            + xv.z * wsm[(k + 2) * 32 + lane] + xv.w * wsm[(k + 3) * 32 + lane];
    }
    float vn = an * rsqrtf((float)cnt[node] + 1.0f);
    float vs = as * rsqrtf((float)cnt[N + node] + 1.0f);
    int sl = lane & 15;
    float vn0 = __shfl(vn, 2 * sl, 32);
    float vn1 = __shfl(vn, 2 * sl + 1, 32);
    float vs0 = __shfl(vs, 2 * sl, 32);
    float vs1 = __shfl(vs, 2 * sl + 1, 32);
    if (lane < 16) {
        __half2 hn = __floats2half2_rn(vn0, vn1);
        __half2 hs = __floats2half2_rn(vs0, vs1);
        size_t on = (size_t)node * 16 + sl;
        size_t os = ((size_t)N + node) * 16 + sl;
        xws[on] = hn;
        acc[on] = hn;
        xws[os] = hs;
        acc[os] = hs;
    }
}

// Merged push-scatter, both edge types, 2 edges per 16-lane group (ILP:
// both 64B gathers in flight before either pk_f16 atomic issues).
__global__ void scatter_kernel(const int* __restrict__ ei_n, const int* __restrict__ ei_s,
                               const __half2* __restrict__ xws, __half2* __restrict__ acc,
                               int N, int En, int Es) {
    unsigned int gid = blockIdx.x * blockDim.x + threadIdx.x;
    int sl = gid & 15;
    int p = (int)(gid >> 4);                  // pair index
    int pn = (En + 1) >> 1;
    int ps = (Es + 1) >> 1;
    if (p >= pn + ps) return;
    const int* src_a;
    const int* dst_a;
    const __half2* xb;
    __half2* ab;
    int e0, E;
    if (p < pn) {
        src_a = ei_n; dst_a = ei_n + En; xb = xws; ab = acc; e0 = 2 * p; E = En;
    } else {
        int q = p - pn;
        src_a = ei_s; dst_a = ei_s + Es;
        xb = xws + (size_t)16 * N; ab = acc + (size_t)16 * N;
        e0 = 2 * q; E = Es;
    }
    int s0 = src_a[e0];
    int d0 = dst_a[e0];
    __half2 w0 = xb[(size_t)s0 * 16 + sl];
    if (e0 + 1 < E) {
        int s1 = src_a[e0 + 1];
        int d1 = dst_a[e0 + 1];
        __half2 w1 = xb[(size_t)s1 * 16 + sl];
        unsafeAtomicAdd(&ab[(size_t)d0 * 16 + sl], w0);
        unsafeAtomicAdd(&ab[(size_t)d1 * 16 + sl], w1);
    } else {
        unsafeAtomicAdd(&ab[(size_t)d0 * 16 + sl], w0);
    }
}

// out[d] = dot(relu(acc_n*dinv_n + b_n + acc_s*dinv_s + b_s), W_lin) + b_lin
__global__ void epilogue_kernel(const __half2* __restrict__ acc, const int* __restrict__ cnt,
                                const float* __restrict__ b_n, const float* __restrict__ b_s,
                                const float* __restrict__ W_lin, const float* __restrict__ b_lin,
                                float* __restrict__ out, int N) {
    int gid = blockIdx.x * blockDim.x + threadIdx.x;
    int node = gid >> 4, sl = gid & 15;
    if (node >= N) return;
    float2 an = __half22float2(acc[(size_t)node * 16 + sl]);
    float2 as = __half22float2(acc[((size_t)N + node) * 16 + sl]);
    float dn = rsqrtf((float)cnt[node] + 1.0f);
    float dsv = rsqrtf((float)cnt[N + node] + 1.0f);
    float h0 = an.x * dn + b_n[2 * sl] + as.x * dsv + b_s[2 * sl];
    float h1 = an.y * dn + b_n[2 * sl + 1] + as.y * dsv + b_s[2 * sl + 1];
    float p = fmaxf(h0, 0.f) * W_lin[2 * sl] + fmaxf(h1, 0.f) * W_lin[2 * sl + 1];
#pragma unroll
    for (int off = 8; off > 0; off >>= 1) p += __shfl_xor(p, off, 16);
    if (sl == 0) out[node] = p + b_lin[0];
}

extern "C" void kernel_launch(void* const* d_in, const int* in_sizes, int n_in,
                              void* d_out, int out_size, void* d_ws, size_t ws_size,
                              hipStream_t stream) {
    const float* x     = (const float*)d_in[0];
    const int*   ei_n  = (const int*)d_in[1];
    const int*   ei_s  = (const int*)d_in[2];
    const float* W_n   = (const float*)d_in[3];
    const float* b_n   = (const float*)d_in[4];
    const float* W_s   = (const float*)d_in[5];
    const float* b_s   = (const float*)d_in[6];
    const float* W_lin = (const float*)d_in[7];
    const float* b_lin = (const float*)d_in[8];
    float* out = (float*)d_out;

    const int N  = in_sizes[0] / 64;   // 100000
    const int En = in_sizes[1] / 2;    // 3200000
    const int Es = in_sizes[2] / 2;    // 3200000
    const int M  = 2 * N;

    // Workspace (4B words), ~26.4 MB: cnt[2N] | xws[2N*16 half2] | acc[2N*16 half2]
    int*     cnt = (int*)d_ws;
    __half2* xws = (__half2*)(cnt + (size_t)M);
    __half2* acc = xws + (size_t)16 * M;

    hipMemsetAsync(cnt, 0, (size_t)M * sizeof(int), stream);

    {
        int nr = (N + HRANGE - 1) / HRANGE;   // 4
        dim3 grid(nr, 32, 2);                 // 256 blocks, 1/CU (128 KB LDS)
        hist_kernel<<<grid, 1024, 0, stream>>>(ei_n + En, ei_s + Es, cnt, N, En);
    }

    xw_kernel<<<(N + 7) / 8, 256, 0, stream>>>(x, W_n, W_s, cnt, xws, acc, N);

    {
        int pairs = ((En + 1) >> 1) + ((Es + 1) >> 1);
        int blocks = (int)(((size_t)pairs * 16 + 255) / 256);
        scatter_kernel<<<blocks, 256, 0, stream>>>(ei_n, ei_s, xws, acc, N, En, Es);
    }

    epilogue_kernel<<<(int)(((size_t)N * 16 + 255) / 256), 256, 0, stream>>>(
        acc, cnt, b_n, b_s, W_lin, b_lin, out, N);
}

// Round 12
// 497.536 us; speedup vs baseline: 2.7724x; 1.0012x over previous
//
#include <hip/hip_runtime.h>
#include <hip/hip_fp16.h>

// N=100000 nodes, 64 in-feats, 32 hidden, E=3200000 edges per type.
// Calibrated model (R1-R11): memory-side atomic RMW throughput is set by
// UNIQUE 64B LINE touches (~19-25 G lines/s), nearly independent of ops/line.
//   push-scatter floor = 6.4M edge-line touches ~= 251-314us.
//   count's 25.5 G lines/s (no gather feeding the atomic) vs scatter's 20.4
//   => the gap is gather-dependency latency. This round: 4-edge ILP per
//   16-lane group (4 x 64B gathers in flight before any atomic issues).
// Pipeline: memset -> hist (LDS-privatized, line-dense flush) -> xw (GEMM,
// pre-scaled by dinv[src], f16x2 pack, seeds acc) -> scatter (pk_f16)
// -> epilogue.

#define HRANGE 32768   // nodes per histogram range (128 KB LDS of int)

__global__ __launch_bounds__(1024, 1)
void hist_kernel(const int* __restrict__ dst_n, const int* __restrict__ dst_s,
                 int* __restrict__ cnt, int N, int E) {
    __shared__ int h[HRANGE];
    for (int i = threadIdx.x; i < HRANGE; i += 1024) h[i] = 0;
    __syncthreads();

    const int range_lo = blockIdx.x * HRANGE;
    const int type = blockIdx.z;
    const int* __restrict__ dst = type ? dst_s : dst_n;
    int* __restrict__ cplane = cnt + (size_t)type * N;

    const int S = gridDim.y;
    int per = (E + S - 1) / S;
    per = (per + 3) & ~3;                       // keep 16B alignment per slice
    const int e0 = blockIdx.y * per;
    const int e1 = min(e0 + per, E);

    int i = e0 + (int)threadIdx.x * 4;
    for (; i + 3 < e1; i += 1024 * 4) {
        int4 v = *(const int4*)(dst + i);
        int d0 = v.x - range_lo, d1 = v.y - range_lo,
            d2 = v.z - range_lo, d3 = v.w - range_lo;
        if ((unsigned)d0 < (unsigned)HRANGE) atomicAdd(&h[d0], 1);
        if ((unsigned)d1 < (unsigned)HRANGE) atomicAdd(&h[d1], 1);
        if ((unsigned)d2 < (unsigned)HRANGE) atomicAdd(&h[d2], 1);
        if ((unsigned)d3 < (unsigned)HRANGE) atomicAdd(&h[d3], 1);
    }
    for (; i < e1; ++i) {
        int d = dst[i] - range_lo;
        if ((unsigned)d < (unsigned)HRANGE) atomicAdd(&h[d], 1);
    }
    __syncthreads();

    const int hi = min(range_lo + HRANGE, N) - range_lo;
    for (int j = threadIdx.x; j < hi; j += 1024) {
        int v = h[j];
        if (v) atomicAdd(&cplane[range_lo + j], v);   // line-dense flush
    }
}

// xws[type][node] = (x[node] @ W_type) * rsqrt(deg+1), packed __half2
// (feats 2sl, 2sl+1 in word sl). acc seeded with same value (self-loop msg).
__global__ void xw_kernel(const float* __restrict__ x,
                          const float* __restrict__ Wn, const float* __restrict__ Ws,
                          const int* __restrict__ cnt,
                          __half2* __restrict__ xws, __half2* __restrict__ acc, int N) {
    __shared__ float wn[64 * 32];
    __shared__ float wsm[64 * 32];
    for (int i = threadIdx.x; i < 64 * 32; i += blockDim.x) {
        wn[i] = Wn[i];
        wsm[i] = Ws[i];
    }
    __syncthreads();
    int lane = threadIdx.x & 31;
    int node = blockIdx.x * (blockDim.x >> 5) + (threadIdx.x >> 5);
    if (node >= N) return;

    const float4* x4 = (const float4*)(x + (size_t)node * 64);
    float an = 0.f, as = 0.f;
#pragma unroll
    for (int k4 = 0; k4 < 16; ++k4) {
        float4 xv = x4[k4];
        int k = k4 * 4;
        an += xv.x * wn[(k + 0) * 32 + lane] + xv.y * wn[(k + 1) * 32 + lane]
            + xv.z * wn[(k + 2) * 32 + lane] + xv.w * wn[(k + 3) * 32 + lane];
        as += xv.x * wsm[(k + 0) * 32 + lane] + xv.y * wsm[(k + 1) * 32 + lane]
            + xv.z * wsm[(k + 2) * 32 + lane] + xv.w * wsm[(k + 3) * 32 + lane];
    }
    float vn = an * rsqrtf((float)cnt[node] + 1.0f);
    float vs = as * rsqrtf((float)cnt[N + node] + 1.0f);
    int sl = lane & 15;
    float vn0 = __shfl(vn, 2 * sl, 32);
    float vn1 = __shfl(vn, 2 * sl + 1, 32);
    float vs0 = __shfl(vs, 2 * sl, 32);
    float vs1 = __shfl(vs, 2 * sl + 1, 32);
    if (lane < 16) {
        __half2 hn = __floats2half2_rn(vn0, vn1);
        __half2 hs = __floats2half2_rn(vs0, vs1);
        size_t on = (size_t)node * 16 + sl;
        size_t os = ((size_t)N + node) * 16 + sl;
        xws[on] = hn;
        acc[on] = hn;
        xws[os] = hs;
        acc[os] = hs;
    }
}

// Merged push-scatter, both edge types, 4 edges per 16-lane group.
// All 4 index pairs then all 4 64B gathers issue before any pk_f16 atomic:
// deep ILP hides gather latency behind the memory-side atomic pipe.
__global__ __launch_bounds__(256)
void scatter_kernel(const int* __restrict__ ei_n, const int* __restrict__ ei_s,
                    const __half2* __restrict__ xws, __half2* __restrict__ acc,
                    int N, int En, int Es) {
    unsigned int gid = blockIdx.x * blockDim.x + threadIdx.x;
    int sl = gid & 15;
    int q = (int)(gid >> 4);                  // quad index
    int qn = (En + 3) >> 2;
    int qs = (Es + 3) >> 2;
    if (q >= qn + qs) return;
    const int* src_a;
    const int* dst_a;
    const __half2* xb;
    __half2* ab;
    int e0, E;
    if (q < qn) {
        src_a = ei_n; dst_a = ei_n + En; xb = xws; ab = acc; e0 = 4 * q; E = En;
    } else {
        int r = q - qn;
        src_a = ei_s; dst_a = ei_s + Es;
        xb = xws + (size_t)16 * N; ab = acc + (size_t)16 * N;
        e0 = 4 * r; E = Es;
    }
    if (e0 + 3 < E) {                         // full quad (common case)
        int s0 = src_a[e0], s1 = src_a[e0 + 1], s2 = src_a[e0 + 2], s3 = src_a[e0 + 3];
        int d0 = dst_a[e0], d1 = dst_a[e0 + 1], d2 = dst_a[e0 + 2], d3 = dst_a[e0 + 3];
        __half2 w0 = xb[(size_t)s0 * 16 + sl];
        __half2 w1 = xb[(size_t)s1 * 16 + sl];
        __half2 w2 = xb[(size_t)s2 * 16 + sl];
        __half2 w3 = xb[(size_t)s3 * 16 + sl];
        unsafeAtomicAdd(&ab[(size_t)d0 * 16 + sl], w0);
        unsafeAtomicAdd(&ab[(size_t)d1 * 16 + sl], w1);
        unsafeAtomicAdd(&ab[(size_t)d2 * 16 + sl], w2);
        unsafeAtomicAdd(&ab[(size_t)d3 * 16 + sl], w3);
    } else {
        for (int e = e0; e < E; ++e) {
            int s = src_a[e];
            int d = dst_a[e];
            __half2 w = xb[(size_t)s * 16 + sl];
            unsafeAtomicAdd(&ab[(size_t)d * 16 + sl], w);
        }
    }
}

// out[d] = dot(relu(acc_n*dinv_n + b_n + acc_s*dinv_s + b_s), W_lin) + b_lin
__global__ void epilogue_kernel(const __half2* __restrict__ acc, const int* __restrict__ cnt,
                                const float* __restrict__ b_n, const float* __restrict__ b_s,
                                const float* __restrict__ W_lin, const float* __restrict__ b_lin,
                                float* __restrict__ out, int N) {
    int gid = blockIdx.x * blockDim.x + threadIdx.x;
    int node = gid >> 4, sl = gid & 15;
    if (node >= N) return;
    float2 an = __half22float2(acc[(size_t)node * 16 + sl]);
    float2 as = __half22float2(acc[((size_t)N + node) * 16 + sl]);
    float dn = rsqrtf((float)cnt[node] + 1.0f);
    float dsv = rsqrtf((float)cnt[N + node] + 1.0f);
    float h0 = an.x * dn + b_n[2 * sl] + as.x * dsv + b_s[2 * sl];
    float h1 = an.y * dn + b_n[2 * sl + 1] + as.y * dsv + b_s[2 * sl + 1];
    float p = fmaxf(h0, 0.f) * W_lin[2 * sl] + fmaxf(h1, 0.f) * W_lin[2 * sl + 1];
#pragma unroll
    for (int off = 8; off > 0; off >>= 1) p += __shfl_xor(p, off, 16);
    if (sl == 0) out[node] = p + b_lin[0];
}

extern "C" void kernel_launch(void* const* d_in, const int* in_sizes, int n_in,
                              void* d_out, int out_size, void* d_ws, size_t ws_size,
                              hipStream_t stream) {
    const float* x     = (const float*)d_in[0];
    const int*   ei_n  = (const int*)d_in[1];
    const int*   ei_s  = (const int*)d_in[2];
    const float* W_n   = (const float*)d_in[3];
    const float* b_n   = (const float*)d_in[4];
    const float* W_s   = (const float*)d_in[5];
    const float* b_s   = (const float*)d_in[6];
    const float* W_lin = (const float*)d_in[7];
    const float* b_lin = (const float*)d_in[8];
    float* out = (float*)d_out;

    const int N  = in_sizes[0] / 64;   // 100000
    const int En = in_sizes[1] / 2;    // 3200000
    const int Es = in_sizes[2] / 2;    // 3200000
    const int M  = 2 * N;

    // Workspace (4B words), ~26.4 MB: cnt[2N] | xws[2N*16 half2] | acc[2N*16 half2]
    int*     cnt = (int*)d_ws;
    __half2* xws = (__half2*)(cnt + (size_t)M);
    __half2* acc = xws + (size_t)16 * M;

    hipMemsetAsync(cnt, 0, (size_t)M * sizeof(int), stream);

    {
        int nr = (N + HRANGE - 1) / HRANGE;   // 4
        dim3 grid(nr, 32, 2);                 // 256 blocks, 1/CU (128 KB LDS)
        hist_kernel<<<grid, 1024, 0, stream>>>(ei_n + En, ei_s + Es, cnt, N, En);
    }

    xw_kernel<<<(N + 7) / 8, 256, 0, stream>>>(x, W_n, W_s, cnt, xws, acc, N);

    {
        int quads = ((En + 3) >> 2) + ((Es + 3) >> 2);
        int blocks = (int)(((size_t)quads * 16 + 255) / 256);
        scatter_kernel<<<blocks, 256, 0, stream>>>(ei_n, ei_s, xws, acc, N, En, Es);
    }

    epilogue_kernel<<<(int)(((size_t)N * 16 + 255) / 256), 256, 0, stream>>>(
        acc, cnt, b_n, b_s, W_lin, b_lin, out, N);
}